// Round 10
// baseline (221.724 us; speedup 1.0000x reference)
//
#include <hip/hip_runtime.h>
#include <hip/hip_bf16.h>

#define TT 4
#define HH 4
#define DD 128
#define KAGG 2048   // TT * HH * DD

typedef __attribute__((ext_vector_type(8))) short short8;
typedef __attribute__((ext_vector_type(4))) float f32x4;
typedef __attribute__((ext_vector_type(4))) unsigned int uint4v;

__device__ __forceinline__ float lrelu(float z) { return z > 0.f ? z : 0.2f * z; }
__device__ __forceinline__ float bf2f(unsigned short u) {
  union { unsigned int i; float f; } v; v.i = ((unsigned int)u) << 16; return v.f;
}
__device__ __forceinline__ unsigned short f2b(float f) {
  union { float f; unsigned int i; } u; u.f = f;
  unsigned int r = u.i + 0x7fff + ((u.i >> 16) & 1);
  return (unsigned short)(r >> 16);
}
__device__ __forceinline__ void unpack8v(uint4v u, float* hv) {
  hv[0] = bf2f((unsigned short)(u.x & 0xffff));
  hv[1] = bf2f((unsigned short)(u.x >> 16));
  hv[2] = bf2f((unsigned short)(u.y & 0xffff));
  hv[3] = bf2f((unsigned short)(u.y >> 16));
  hv[4] = bf2f((unsigned short)(u.z & 0xffff));
  hv[5] = bf2f((unsigned short)(u.z >> 16));
  hv[6] = bf2f((unsigned short)(u.w & 0xffff));
  hv[7] = bf2f((unsigned short)(u.w >> 16));
}

// ======== prologue: convx | prepw (Gfrag, Pall, cbias) | hist, one launch
__global__ __launch_bounds__(256) void prologue_kernel(
    const float* __restrict__ x, unsigned short* __restrict__ xb, int total4,
    const float* __restrict__ Wg, const float* __restrict__ a_s,
    const float* __restrict__ a_d, const float* __restrict__ W_fuse,
    const float* __restrict__ b_gat, const float* __restrict__ etw,
    const float* __restrict__ b_fuse, unsigned short* __restrict__ Gfrag,
    unsigned short* __restrict__ Pall, float* __restrict__ cbias,
    const int* __restrict__ dst, const int* __restrict__ attr,
    int* __restrict__ deg, int E, int N) {
  int bid = blockIdx.x;
  const int nconv = (total4 + 255) >> 8;
  if (bid < nconv) {                       // ---- convx
    int i = bid * 256 + threadIdx.x;
    if (i < total4) {
      float4 v = ((const float4*)x)[i];
      ushort4 o;
      o.x = f2b(v.x); o.y = f2b(v.y); o.z = f2b(v.z); o.w = f2b(v.w);
      ((ushort4*)xb)[i] = o;
    }
    return;
  }
  bid -= nconv;
  if (bid < 1041) {                        // ---- prepw
    float e0 = etw[0], e1 = etw[1], e2 = etw[2], e3 = etw[3];
    float mx = fmaxf(fmaxf(e0, e1), fmaxf(e2, e3));
    float w0 = __expf(e0 - mx), w1 = __expf(e1 - mx), w2 = __expf(e2 - mx),
          w3 = __expf(e3 - mx);
    float inv = 1.f / (w0 + w1 + w2 + w3);
    float wts[4] = {w0 * inv, w1 * inv, w2 * inv, w3 * inv};
    if (bid < 1024) {                      // Gfrag: 512 frags * 512 shorts
      int idx = bid * 256 + threadIdx.x;
      int f = idx >> 9, l = (idx >> 3) & 63, j = idx & 7;
      int kt = f >> 5, kk = (f >> 3) & 3, n = f & 7;
      int K = kt * 128 + kk * 32 + (l >> 4) * 8 + j;
      int col = n * 16 + (l & 15);
      int t = K >> 9, head = (K >> 7) & 3, k = K & 127;
      const float* wr = Wg + (size_t)t * 65536 + k * 512 + head * 128;
      const float* wf = W_fuse + (size_t)t * 128 * 128 + col;
      float s = 0.f;
      for (int m = 0; m < 128; ++m) s += wr[m] * wf[(size_t)m * 128];
      Gfrag[idx] = f2b(0.25f * wts[t] * s);
    } else if (bid < 1040) {               // Pall: 32*128
      int idx = (bid - 1024) * 256 + threadIdx.x;
      int c = idx >> 7, k = idx & 127;
      int t = c >> 3, jj = c & 7, head = jj & 3;
      const float* av = ((jj < 4) ? a_s : a_d) + (t * 4 + head) * 128;
      const float* wr = Wg + (size_t)t * 65536 + k * 512 + head * 128;
      float s = 0.f;
      for (int m = 0; m < 128; ++m) s += wr[m] * av[m];
      Pall[c * 128 + k] = f2b(s);
    } else {                               // cbias
      int j = threadIdx.x;
      if (j < 128) {
        float s = b_fuse[j];
        for (int t = 0; t < 4; ++t) {
          float st = 0.f;
          for (int m = 0; m < 128; ++m)
            st += b_gat[t * 128 + m] * W_fuse[(size_t)(t * 128 + m) * 128 + j];
          s += wts[t] * st;
        }
        cbias[j] = s;
      }
    }
    return;
  }
  bid -= 1041;                             // ---- hist
  int e = bid * 256 + threadIdx.x;
  if (e < E) atomicAdd(&deg[attr[e] * N + dst[e]], 1);
}

// ======== single-pass scan: block-local scan + atomic chunk-base allocation.
// (Bucket order is irrelevant -> any disjoint allocation is correct.)
__global__ __launch_bounds__(1024) void scanfused_kernel(
    const int* __restrict__ deg, int* __restrict__ rowptr,
    int* __restrict__ cursor, int* __restrict__ gcur, int M) {
  __shared__ int sh[1024];
  __shared__ int base;
  int i = blockIdx.x * 1024 + threadIdx.x;
  int v = (i < M) ? deg[i] : 0;
  sh[threadIdx.x] = v;
  __syncthreads();
  for (int off = 1; off < 1024; off <<= 1) {
    int xx = (threadIdx.x >= off) ? sh[threadIdx.x - off] : 0;
    __syncthreads();
    sh[threadIdx.x] += xx;
    __syncthreads();
  }
  if (threadIdx.x == 1023) base = atomicAdd(gcur, sh[1023]);
  __syncthreads();
  if (i < M) {
    int r = base + sh[threadIdx.x] - v;
    rowptr[i] = r;
    cursor[i] = r;
  }
}

// ======== scatter | alpha (merged)
__global__ __launch_bounds__(256) void scatter_alpha_kernel(
    const int* __restrict__ src, const int* __restrict__ dst,
    const int* __restrict__ attr, int* __restrict__ cursor,
    int* __restrict__ slist, const unsigned short* __restrict__ xb,
    const unsigned short* __restrict__ Pall, float* __restrict__ as_,
    float* __restrict__ ad_, int E, int N) {
  __shared__ uint4 ldsv[2048];  // 32KB (alpha branch only)
  int bid = blockIdx.x;
  const int nsc = (E + 255) >> 8;
  if (bid < nsc) {                         // ---- scatter
    int e = bid * 256 + threadIdx.x;
    if (e < E) {
      int p = atomicAdd(&cursor[attr[e] * N + dst[e]], 1);
      slist[p] = src[e];
    }
    return;
  }
  bid -= nsc;                              // ---- alpha via MFMA
  unsigned char* lds = (unsigned char*)ldsv;
  const int n0 = bid * 128;
  const int tid = threadIdx.x, lane = tid & 63, wid = tid >> 6;
  const int lr = lane & 15, lg = lane >> 4;
#pragma unroll
  for (int i = 0; i < 8; ++i) {
    int chunk = tid + i * 256;
    int row = chunk >> 4, k16 = chunk & 15;
    int gr = n0 + row;
    uint4 v = make_uint4(0, 0, 0, 0);
    if (gr < N) v = *(const uint4*)(xb + (size_t)gr * DD + k16 * 8);
    *(uint4*)(lds + ((row * 256 + k16 * 16) ^ ((row & 7) << 4))) = v;
  }
  __syncthreads();
  f32x4 acc[2][2] = {};
#pragma unroll
  for (int kk = 0; kk < 4; ++kk) {
    short8 a[2], b[2];
#pragma unroll
    for (int m = 0; m < 2; ++m) {
      int row = wid * 32 + m * 16 + lr;
      a[m] = *(const short8*)(lds + ((row * 256 + kk * 64 + (lg << 4)) ^ ((row & 7) << 4)));
    }
#pragma unroll
    for (int n = 0; n < 2; ++n) {
      int c = n * 16 + lr;
      b[n] = *(const short8*)(Pall + c * DD + kk * 32 + lg * 8);
    }
#pragma unroll
    for (int m = 0; m < 2; ++m)
#pragma unroll
      for (int n = 0; n < 2; ++n)
        acc[m][n] = __builtin_amdgcn_mfma_f32_16x16x32_bf16(a[m], b[n], acc[m][n], 0, 0, 0);
  }
#pragma unroll
  for (int m = 0; m < 2; ++m)
#pragma unroll
    for (int n = 0; n < 2; ++n) {
      int c = n * 16 + lr;
      int t = c >> 3, jj = c & 7, head = jj & 3;
      float* dstp = (jj & 4) ? ad_ : as_;
#pragma unroll
      for (int r = 0; r < 4; ++r) {
        int gr = n0 + wid * 32 + m * 16 + lg * 4 + r;
        if (gr < N) dstp[((size_t)t * N + gr) * 4 + head] = acc[m][n][r];
      }
    }
}

// ======== gather: one wave per (t, dst); deg-0 fast path; nontemporal stores
__global__ __launch_bounds__(256) void gather_kernel(
    const int* __restrict__ slist, const int* __restrict__ rowptr,
    const int* __restrict__ deg, const float* __restrict__ as_,
    const float* __restrict__ ad_, const unsigned short* __restrict__ xb,
    unsigned short* __restrict__ AGG, int N) {
  int t = blockIdx.y;
  int d = blockIdx.x * 4 + (threadIdx.x >> 6);
  if (d >= N) return;
  int lane = threadIdx.x & 63;
  int head = lane >> 4;
  int dofs = (lane & 15) * 8;
  size_t tn = (size_t)t * N;
  uint4v* outp = (uint4v*)(AGG + (size_t)d * KAGG + t * 512 + lane * 8);

  int base = rowptr[tn + d], dg = deg[tn + d];
  if (dg == 0) {   // softmax over {self} = 1 -> AGG row = xb row (all heads)
    uint4v u = *(const uint4v*)(xb + (size_t)d * DD + dofs);
    __builtin_nontemporal_store(u, outp);
    return;
  }

  float adh = ad_[(tn + d) * 4 + head];
  float es = __expf(lrelu(as_[(tn + d) * 4 + head] + adh));
  float den = es;
  float acc8[8], hv[8];
  unpack8v(*(const uint4v*)(xb + (size_t)d * DD + dofs), hv);
#pragma unroll
  for (int j = 0; j < 8; ++j) acc8[j] = es * hv[j];

  int i = 0;
  for (; i + 1 < dg; i += 2) {
    int s0 = slist[base + i], s1 = slist[base + i + 1];
    float av0 = as_[(tn + s0) * 4 + head];
    float av1 = as_[(tn + s1) * 4 + head];
    uint4v u0 = *(const uint4v*)(xb + (size_t)s0 * DD + dofs);
    uint4v u1 = *(const uint4v*)(xb + (size_t)s1 * DD + dofs);
    float q0 = __expf(lrelu(av0 + adh));
    float q1 = __expf(lrelu(av1 + adh));
    den += q0 + q1;
    unpack8v(u0, hv);
#pragma unroll
    for (int j = 0; j < 8; ++j) acc8[j] += q0 * hv[j];
    unpack8v(u1, hv);
#pragma unroll
    for (int j = 0; j < 8; ++j) acc8[j] += q1 * hv[j];
  }
  if (i < dg) {
    int s = slist[base + i];
    float av = as_[(tn + s) * 4 + head];
    uint4v u = *(const uint4v*)(xb + (size_t)s * DD + dofs);
    float q = __expf(lrelu(av + adh));
    den += q;
    unpack8v(u, hv);
#pragma unroll
    for (int j = 0; j < 8; ++j) acc8[j] += q * hv[j];
  }

  float r = 1.f / den;
  uint4v o;
  o.x = (unsigned)f2b(acc8[0] * r) | ((unsigned)f2b(acc8[1] * r) << 16);
  o.y = (unsigned)f2b(acc8[2] * r) | ((unsigned)f2b(acc8[3] * r) << 16);
  o.z = (unsigned)f2b(acc8[4] * r) | ((unsigned)f2b(acc8[5] * r) << 16);
  o.w = (unsigned)f2b(acc8[6] * r) | ((unsigned)f2b(acc8[7] * r) << 16);
  __builtin_nontemporal_store(o, outp);
}

// ======== final GEMM [N,2048]@[2048,128] + cbias + LayerNorm + ReLU
// 128 rows/block, 4 waves. B dbuf in LDS; A reg-prefetched (nontemporal).
__global__ __launch_bounds__(256) void gemmln_kernel(
    const unsigned short* __restrict__ AGG, const unsigned short* __restrict__ Gfrag,
    const float* __restrict__ cbias, const float* __restrict__ gamma,
    const float* __restrict__ beta, float* __restrict__ out, int N) {
  __shared__ uint4 bbuf[2][2048];   // 2 x 32KB B tiles
  const int n0 = blockIdx.x * 128;
  const int tid = threadIdx.x, lane = tid & 63, wid = tid >> 6;
  const int lr = lane & 15, lg = lane >> 4;
  const int wrow = n0 + wid * 32;

  uint4 bn[8], ac[8];
  uint4v an[8];
#pragma unroll
  for (int i = 0; i < 8; ++i)
    bn[i] = *(const uint4*)(Gfrag + (size_t)(i * 256 + tid) * 8);
#pragma unroll
  for (int i = 0; i < 8; ++i) {
    int m = i >> 2, kk = i & 3;
    int gr = wrow + m * 16 + lr;
    an[i] = (uint4v){0, 0, 0, 0};
    if (gr < N)
      an[i] = __builtin_nontemporal_load(
          (const uint4v*)(AGG + (size_t)gr * KAGG + kk * 32 + lg * 8));
  }
#pragma unroll
  for (int i = 0; i < 8; ++i) bbuf[0][i * 256 + tid] = bn[i];
  __syncthreads();
#pragma unroll
  for (int i = 0; i < 8; ++i) ac[i] = *(uint4*)&an[i];

  f32x4 acc[2][8] = {};
  int cur = 0;
  for (int kt = 0; kt < 16; ++kt) {
    if (kt < 15) {
#pragma unroll
      for (int i = 0; i < 8; ++i)
        bn[i] = *(const uint4*)(Gfrag + (size_t)(kt + 1) * 16384 + (size_t)(i * 256 + tid) * 8);
#pragma unroll
      for (int i = 0; i < 8; ++i) {
        int m = i >> 2, kk = i & 3;
        int gr = wrow + m * 16 + lr;
        an[i] = (uint4v){0, 0, 0, 0};
        if (gr < N)
          an[i] = __builtin_nontemporal_load(
              (const uint4v*)(AGG + (size_t)gr * KAGG + (kt + 1) * 128 + kk * 32 + lg * 8));
      }
    }
    const unsigned char* lds = (const unsigned char*)bbuf[cur];
#pragma unroll
    for (int kk = 0; kk < 4; ++kk) {
      short8 a0 = *(const short8*)&ac[0 * 4 + kk];
      short8 a1 = *(const short8*)&ac[1 * 4 + kk];
#pragma unroll
      for (int n = 0; n < 8; ++n) {
        short8 b = *(const short8*)(lds + (kk * 8 + n) * 1024 + lane * 16);
        acc[0][n] = __builtin_amdgcn_mfma_f32_16x16x32_bf16(a0, b, acc[0][n], 0, 0, 0);
        acc[1][n] = __builtin_amdgcn_mfma_f32_16x16x32_bf16(a1, b, acc[1][n], 0, 0, 0);
      }
    }
    if (kt < 15) {
#pragma unroll
      for (int i = 0; i < 8; ++i) bbuf[cur ^ 1][i * 256 + tid] = bn[i];
      __syncthreads();
      cur ^= 1;
#pragma unroll
      for (int i = 0; i < 8; ++i) ac[i] = *(uint4*)&an[i];
    }
  }

  float cb[8], gm[8], bt[8];
#pragma unroll
  for (int n = 0; n < 8; ++n) {
    cb[n] = cbias[n * 16 + lr];
    gm[n] = gamma[n * 16 + lr];
    bt[n] = beta[n * 16 + lr];
  }
#pragma unroll
  for (int m = 0; m < 2; ++m)
#pragma unroll
    for (int rr = 0; rr < 4; ++rr) {
      float y[8];
      float s = 0.f, ss = 0.f;
#pragma unroll
      for (int n = 0; n < 8; ++n) {
        y[n] = acc[m][n][rr] + cb[n];
        s += y[n];
        ss += y[n] * y[n];
      }
#pragma unroll
      for (int mask = 1; mask <= 8; mask <<= 1) {
        s += __shfl_xor(s, mask);
        ss += __shfl_xor(ss, mask);
      }
      float mean = s * (1.f / 128.f);
      float var = ss * (1.f / 128.f) - mean * mean;
      float rstd = rsqrtf(var + 1e-5f);
      int gr = wrow + m * 16 + lg * 4 + rr;
      if (gr < N) {
#pragma unroll
        for (int n = 0; n < 8; ++n) {
          float v = (y[n] - mean) * rstd * gm[n] + bt[n];
          out[(size_t)gr * DD + n * 16 + lr] = fmaxf(0.f, v);
        }
      }
    }
}

extern "C" void kernel_launch(void* const* d_in, const int* in_sizes, int n_in,
                              void* d_out, int out_size, void* d_ws, size_t ws_size,
                              hipStream_t stream) {
  const float* x      = (const float*)d_in[0];
  const int*   ei     = (const int*)d_in[1];
  const int*   attr   = (const int*)d_in[2];
  const float* Wg     = (const float*)d_in[3];
  const float* a_src  = (const float*)d_in[4];
  const float* a_dst  = (const float*)d_in[5];
  const float* b_gat  = (const float*)d_in[6];
  const float* etw    = (const float*)d_in[7];
  const float* W_fuse = (const float*)d_in[8];
  const float* b_fuse = (const float*)d_in[9];
  const float* gamma  = (const float*)d_in[10];
  const float* beta   = (const float*)d_in[11];

  const int N = in_sizes[0] / DD;
  const int E = in_sizes[2];
  const int* src = ei;
  const int* dst = ei + E;
  const int M = TT * N;

  char* ws = (char*)d_ws;
  size_t off = 0;
  auto alloc = [&](size_t bytes) {
    void* p = ws + off;
    off += (bytes + 255) & ~(size_t)255;
    return p;
  };
  unsigned short* AGG   = (unsigned short*)alloc((size_t)N * KAGG * 2);      // 204.8MB
  unsigned short* xb    = (unsigned short*)alloc((size_t)N * DD * 2);        // 12.8MB
  unsigned short* Gfrag = (unsigned short*)alloc((size_t)512 * 512 * 2);     // 512KB
  unsigned short* Pall  = (unsigned short*)alloc((size_t)32 * DD * 2);       // 8KB
  float* cbias          = (float*)alloc(128 * sizeof(float));
  float* as_            = (float*)alloc((size_t)TT * N * 4 * sizeof(float)); // 3.2MB
  float* ad_            = (float*)alloc((size_t)TT * N * 4 * sizeof(float));
  int* deg              = (int*)alloc((size_t)(M + 1) * sizeof(int));        // +1 = gcur
  int* rowptr           = (int*)alloc((size_t)M * sizeof(int));
  int* cursor           = (int*)alloc((size_t)M * sizeof(int));
  int* slist            = (int*)alloc((size_t)E * sizeof(int));              // 1.3MB

  hipMemsetAsync(deg, 0, (size_t)(M + 1) * sizeof(int), stream);

  int total4x = N * DD / 4;
  int nconv = (total4x + 255) / 256;
  int nhist = (E + 255) / 256;
  prologue_kernel<<<nconv + 1041 + nhist, 256, 0, stream>>>(
      x, xb, total4x, Wg, a_src, a_dst, W_fuse, b_gat, etw, b_fuse,
      Gfrag, Pall, cbias, dst, attr, deg, E, N);

  scanfused_kernel<<<(M + 1023) / 1024, 1024, 0, stream>>>(deg, rowptr, cursor,
                                                           deg + M, M);

  int nalpha = (N + 127) / 128;
  scatter_alpha_kernel<<<nhist + nalpha, 256, 0, stream>>>(
      src, dst, attr, cursor, slist, xb, Pall, as_, ad_, E, N);

  dim3 ggrid((N + 3) / 4, TT);
  gather_kernel<<<ggrid, 256, 0, stream>>>(slist, rowptr, deg, as_, ad_, xb, AGG, N);

  gemmln_kernel<<<(N + 127) / 128, 256, 0, stream>>>(AGG, Gfrag, cbias, gamma, beta,
                                                     (float*)d_out, N);
}

// Round 11
// 198.184 us; speedup vs baseline: 1.1188x; 1.1188x over previous
//
#include <hip/hip_runtime.h>
#include <hip/hip_bf16.h>

#define TT 4
#define HH 4
#define DD 128
#define KAGG 2048   // TT * HH * DD

typedef __attribute__((ext_vector_type(8))) short short8;
typedef __attribute__((ext_vector_type(4))) float f32x4;
typedef __attribute__((ext_vector_type(4))) unsigned int uint4v;

__device__ __forceinline__ float lrelu(float z) { return z > 0.f ? z : 0.2f * z; }
__device__ __forceinline__ float bf2f(unsigned short u) {
  union { unsigned int i; float f; } v; v.i = ((unsigned int)u) << 16; return v.f;
}
__device__ __forceinline__ unsigned short f2b(float f) {
  union { float f; unsigned int i; } u; u.f = f;
  unsigned int r = u.i + 0x7fff + ((u.i >> 16) & 1);
  return (unsigned short)(r >> 16);
}
__device__ __forceinline__ void unpack8v(uint4v u, float* hv) {
  hv[0] = bf2f((unsigned short)(u.x & 0xffff));
  hv[1] = bf2f((unsigned short)(u.x >> 16));
  hv[2] = bf2f((unsigned short)(u.y & 0xffff));
  hv[3] = bf2f((unsigned short)(u.y >> 16));
  hv[4] = bf2f((unsigned short)(u.z & 0xffff));
  hv[5] = bf2f((unsigned short)(u.z >> 16));
  hv[6] = bf2f((unsigned short)(u.w & 0xffff));
  hv[7] = bf2f((unsigned short)(u.w >> 16));
}

// ======== prologue: convx | prepw (Gfrag, Pall, cbias) | hist, one launch
__global__ __launch_bounds__(256) void prologue_kernel(
    const float* __restrict__ x, unsigned short* __restrict__ xb, int total4,
    const float* __restrict__ Wg, const float* __restrict__ a_s,
    const float* __restrict__ a_d, const float* __restrict__ W_fuse,
    const float* __restrict__ b_gat, const float* __restrict__ etw,
    const float* __restrict__ b_fuse, unsigned short* __restrict__ Gfrag,
    unsigned short* __restrict__ Pall, float* __restrict__ cbias,
    const int* __restrict__ dst, const int* __restrict__ attr,
    int* __restrict__ deg, int E, int N) {
  int bid = blockIdx.x;
  const int nconv = (total4 + 255) >> 8;
  if (bid < nconv) {                       // ---- convx
    int i = bid * 256 + threadIdx.x;
    if (i < total4) {
      float4 v = ((const float4*)x)[i];
      ushort4 o;
      o.x = f2b(v.x); o.y = f2b(v.y); o.z = f2b(v.z); o.w = f2b(v.w);
      ((ushort4*)xb)[i] = o;
    }
    return;
  }
  bid -= nconv;
  if (bid < 1041) {                        // ---- prepw
    float e0 = etw[0], e1 = etw[1], e2 = etw[2], e3 = etw[3];
    float mx = fmaxf(fmaxf(e0, e1), fmaxf(e2, e3));
    float w0 = __expf(e0 - mx), w1 = __expf(e1 - mx), w2 = __expf(e2 - mx),
          w3 = __expf(e3 - mx);
    float inv = 1.f / (w0 + w1 + w2 + w3);
    float wts[4] = {w0 * inv, w1 * inv, w2 * inv, w3 * inv};
    if (bid < 1024) {                      // Gfrag: 512 frags * 512 shorts
      int idx = bid * 256 + threadIdx.x;
      int f = idx >> 9, l = (idx >> 3) & 63, j = idx & 7;
      int kt = f >> 5, kk = (f >> 3) & 3, n = f & 7;
      int K = kt * 128 + kk * 32 + (l >> 4) * 8 + j;
      int col = n * 16 + (l & 15);
      int t = K >> 9, head = (K >> 7) & 3, k = K & 127;
      const float* wr = Wg + (size_t)t * 65536 + k * 512 + head * 128;
      const float* wf = W_fuse + (size_t)t * 128 * 128 + col;
      float s = 0.f;
      for (int m = 0; m < 128; ++m) s += wr[m] * wf[(size_t)m * 128];
      Gfrag[idx] = f2b(0.25f * wts[t] * s);
    } else if (bid < 1040) {               // Pall: 32*128
      int idx = (bid - 1024) * 256 + threadIdx.x;
      int c = idx >> 7, k = idx & 127;
      int t = c >> 3, jj = c & 7, head = jj & 3;
      const float* av = ((jj < 4) ? a_s : a_d) + (t * 4 + head) * 128;
      const float* wr = Wg + (size_t)t * 65536 + k * 512 + head * 128;
      float s = 0.f;
      for (int m = 0; m < 128; ++m) s += wr[m] * av[m];
      Pall[c * 128 + k] = f2b(s);
    } else {                               // cbias
      int j = threadIdx.x;
      if (j < 128) {
        float s = b_fuse[j];
        for (int t = 0; t < 4; ++t) {
          float st = 0.f;
          for (int m = 0; m < 128; ++m)
            st += b_gat[t * 128 + m] * W_fuse[(size_t)(t * 128 + m) * 128 + j];
          s += wts[t] * st;
        }
        cbias[j] = s;
      }
    }
    return;
  }
  bid -= 1041;                             // ---- hist
  int e = bid * 256 + threadIdx.x;
  if (e < E) atomicAdd(&deg[attr[e] * N + dst[e]], 1);
}

// ======== single-pass scan: block-local scan + atomic chunk-base allocation.
__global__ __launch_bounds__(1024) void scanfused_kernel(
    const int* __restrict__ deg, int* __restrict__ rowptr,
    int* __restrict__ cursor, int* __restrict__ gcur, int M) {
  __shared__ int sh[1024];
  __shared__ int base;
  int i = blockIdx.x * 1024 + threadIdx.x;
  int v = (i < M) ? deg[i] : 0;
  sh[threadIdx.x] = v;
  __syncthreads();
  for (int off = 1; off < 1024; off <<= 1) {
    int xx = (threadIdx.x >= off) ? sh[threadIdx.x - off] : 0;
    __syncthreads();
    sh[threadIdx.x] += xx;
    __syncthreads();
  }
  if (threadIdx.x == 1023) base = atomicAdd(gcur, sh[1023]);
  __syncthreads();
  if (i < M) {
    int r = base + sh[threadIdx.x] - v;
    rowptr[i] = r;
    cursor[i] = r;
  }
}

// ======== scatter | alpha (merged)
__global__ __launch_bounds__(256) void scatter_alpha_kernel(
    const int* __restrict__ src, const int* __restrict__ dst,
    const int* __restrict__ attr, int* __restrict__ cursor,
    int* __restrict__ slist, const unsigned short* __restrict__ xb,
    const unsigned short* __restrict__ Pall, float* __restrict__ as_,
    float* __restrict__ ad_, int E, int N) {
  __shared__ uint4 ldsv[2048];  // 32KB (alpha branch only)
  int bid = blockIdx.x;
  const int nsc = (E + 255) >> 8;
  if (bid < nsc) {                         // ---- scatter
    int e = bid * 256 + threadIdx.x;
    if (e < E) {
      int p = atomicAdd(&cursor[attr[e] * N + dst[e]], 1);
      slist[p] = src[e];
    }
    return;
  }
  bid -= nsc;                              // ---- alpha via MFMA
  unsigned char* lds = (unsigned char*)ldsv;
  const int n0 = bid * 128;
  const int tid = threadIdx.x, lane = tid & 63, wid = tid >> 6;
  const int lr = lane & 15, lg = lane >> 4;
#pragma unroll
  for (int i = 0; i < 8; ++i) {
    int chunk = tid + i * 256;
    int row = chunk >> 4, k16 = chunk & 15;
    int gr = n0 + row;
    uint4 v = make_uint4(0, 0, 0, 0);
    if (gr < N) v = *(const uint4*)(xb + (size_t)gr * DD + k16 * 8);
    *(uint4*)(lds + ((row * 256 + k16 * 16) ^ ((row & 7) << 4))) = v;
  }
  __syncthreads();
  f32x4 acc[2][2] = {};
#pragma unroll
  for (int kk = 0; kk < 4; ++kk) {
    short8 a[2], b[2];
#pragma unroll
    for (int m = 0; m < 2; ++m) {
      int row = wid * 32 + m * 16 + lr;
      a[m] = *(const short8*)(lds + ((row * 256 + kk * 64 + (lg << 4)) ^ ((row & 7) << 4)));
    }
#pragma unroll
    for (int n = 0; n < 2; ++n) {
      int c = n * 16 + lr;
      b[n] = *(const short8*)(Pall + c * DD + kk * 32 + lg * 8);
    }
#pragma unroll
    for (int m = 0; m < 2; ++m)
#pragma unroll
      for (int n = 0; n < 2; ++n)
        acc[m][n] = __builtin_amdgcn_mfma_f32_16x16x32_bf16(a[m], b[n], acc[m][n], 0, 0, 0);
  }
#pragma unroll
  for (int m = 0; m < 2; ++m)
#pragma unroll
    for (int n = 0; n < 2; ++n) {
      int c = n * 16 + lr;
      int t = c >> 3, jj = c & 7, head = jj & 3;
      float* dstp = (jj & 4) ? ad_ : as_;
#pragma unroll
      for (int r = 0; r < 4; ++r) {
        int gr = n0 + wid * 32 + m * 16 + lg * 4 + r;
        if (gr < N) dstp[((size_t)t * N + gr) * 4 + head] = acc[m][n][r];
      }
    }
}

// ======== gather: 16 lanes per (t,d) unit, 4 units/wave — dedup'd xb reads.
// Each lane owns 8 cols, computes all 4 heads in registers.
__global__ __launch_bounds__(256) void gather_kernel(
    const int* __restrict__ slist, const int* __restrict__ rowptr,
    const int* __restrict__ deg, const float* __restrict__ as_,
    const float* __restrict__ ad_, const unsigned short* __restrict__ xb,
    unsigned short* __restrict__ AGG, int N) {
  int t = blockIdx.y;
  int lane = threadIdx.x & 63;
  int u = lane >> 4, c16 = lane & 15;
  int d = blockIdx.x * 16 + (threadIdx.x >> 6) * 4 + u;
  if (d >= N) return;
  size_t tn = (size_t)t * N;
  int dofs = c16 * 8;
  unsigned short* outp = AGG + (size_t)d * KAGG + t * 512 + dofs;

  int base = rowptr[tn + d], dg = deg[tn + d];
  uint4v uself = *(const uint4v*)(xb + (size_t)d * DD + dofs);
  if (dg == 0) {   // softmax over {self} = 1 -> AGG row slice = xb row, all heads
#pragma unroll
    for (int h = 0; h < 4; ++h) *(uint4v*)(outp + h * DD) = uself;
    return;
  }

  float4 ad4 = *(const float4*)(ad_ + (tn + d) * 4);
  float4 av = *(const float4*)(as_ + (tn + d) * 4);
  float q[4], den[4], hv[8], acc[4][8];
  q[0] = __expf(lrelu(av.x + ad4.x));
  q[1] = __expf(lrelu(av.y + ad4.y));
  q[2] = __expf(lrelu(av.z + ad4.z));
  q[3] = __expf(lrelu(av.w + ad4.w));
  unpack8v(uself, hv);
#pragma unroll
  for (int h = 0; h < 4; ++h) {
    den[h] = q[h];
#pragma unroll
    for (int j = 0; j < 8; ++j) acc[h][j] = q[h] * hv[j];
  }

  int i = 0;
  for (; i + 1 < dg; i += 2) {
    int s0 = slist[base + i], s1 = slist[base + i + 1];
    float4 a0 = *(const float4*)(as_ + (tn + s0) * 4);
    float4 a1 = *(const float4*)(as_ + (tn + s1) * 4);
    uint4v u0 = *(const uint4v*)(xb + (size_t)s0 * DD + dofs);
    uint4v u1 = *(const uint4v*)(xb + (size_t)s1 * DD + dofs);
    float q0[4], q1[4];
    q0[0] = __expf(lrelu(a0.x + ad4.x));
    q0[1] = __expf(lrelu(a0.y + ad4.y));
    q0[2] = __expf(lrelu(a0.z + ad4.z));
    q0[3] = __expf(lrelu(a0.w + ad4.w));
    q1[0] = __expf(lrelu(a1.x + ad4.x));
    q1[1] = __expf(lrelu(a1.y + ad4.y));
    q1[2] = __expf(lrelu(a1.z + ad4.z));
    q1[3] = __expf(lrelu(a1.w + ad4.w));
#pragma unroll
    for (int h = 0; h < 4; ++h) den[h] += q0[h] + q1[h];
    unpack8v(u0, hv);
#pragma unroll
    for (int h = 0; h < 4; ++h)
#pragma unroll
      for (int j = 0; j < 8; ++j) acc[h][j] += q0[h] * hv[j];
    unpack8v(u1, hv);
#pragma unroll
    for (int h = 0; h < 4; ++h)
#pragma unroll
      for (int j = 0; j < 8; ++j) acc[h][j] += q1[h] * hv[j];
  }
  if (i < dg) {
    int s = slist[base + i];
    float4 a = *(const float4*)(as_ + (tn + s) * 4);
    uint4v ue = *(const uint4v*)(xb + (size_t)s * DD + dofs);
    float qe[4];
    qe[0] = __expf(lrelu(a.x + ad4.x));
    qe[1] = __expf(lrelu(a.y + ad4.y));
    qe[2] = __expf(lrelu(a.z + ad4.z));
    qe[3] = __expf(lrelu(a.w + ad4.w));
#pragma unroll
    for (int h = 0; h < 4; ++h) den[h] += qe[h];
    unpack8v(ue, hv);
#pragma unroll
    for (int h = 0; h < 4; ++h)
#pragma unroll
      for (int j = 0; j < 8; ++j) acc[h][j] += qe[h] * hv[j];
  }

#pragma unroll
  for (int h = 0; h < 4; ++h) {
    float r = 1.f / den[h];
    uint4v o;
    o.x = (unsigned)f2b(acc[h][0] * r) | ((unsigned)f2b(acc[h][1] * r) << 16);
    o.y = (unsigned)f2b(acc[h][2] * r) | ((unsigned)f2b(acc[h][3] * r) << 16);
    o.z = (unsigned)f2b(acc[h][4] * r) | ((unsigned)f2b(acc[h][5] * r) << 16);
    o.w = (unsigned)f2b(acc[h][6] * r) | ((unsigned)f2b(acc[h][7] * r) << 16);
    *(uint4v*)(outp + h * DD) = o;
  }
}

// ======== final GEMM [N,2048]@[2048,128] + cbias + LayerNorm + ReLU
// 128 rows/block, 4 waves. B dbuf in LDS; A reg-prefetched (regular loads).
__global__ __launch_bounds__(256) void gemmln_kernel(
    const unsigned short* __restrict__ AGG, const unsigned short* __restrict__ Gfrag,
    const float* __restrict__ cbias, const float* __restrict__ gamma,
    const float* __restrict__ beta, float* __restrict__ out, int N) {
  __shared__ uint4 bbuf[2][2048];   // 2 x 32KB B tiles
  const int n0 = blockIdx.x * 128;
  const int tid = threadIdx.x, lane = tid & 63, wid = tid >> 6;
  const int lr = lane & 15, lg = lane >> 4;
  const int wrow = n0 + wid * 32;

  uint4 bn[8], an[8], ac[8];
#pragma unroll
  for (int i = 0; i < 8; ++i)
    bn[i] = *(const uint4*)(Gfrag + (size_t)(i * 256 + tid) * 8);
#pragma unroll
  for (int i = 0; i < 8; ++i) {
    int m = i >> 2, kk = i & 3;
    int gr = wrow + m * 16 + lr;
    an[i] = make_uint4(0, 0, 0, 0);
    if (gr < N) an[i] = *(const uint4*)(AGG + (size_t)gr * KAGG + kk * 32 + lg * 8);
  }
#pragma unroll
  for (int i = 0; i < 8; ++i) bbuf[0][i * 256 + tid] = bn[i];
  __syncthreads();
#pragma unroll
  for (int i = 0; i < 8; ++i) ac[i] = an[i];

  f32x4 acc[2][8] = {};
  int cur = 0;
  for (int kt = 0; kt < 16; ++kt) {
    if (kt < 15) {
#pragma unroll
      for (int i = 0; i < 8; ++i)
        bn[i] = *(const uint4*)(Gfrag + (size_t)(kt + 1) * 16384 + (size_t)(i * 256 + tid) * 8);
#pragma unroll
      for (int i = 0; i < 8; ++i) {
        int m = i >> 2, kk = i & 3;
        int gr = wrow + m * 16 + lr;
        an[i] = make_uint4(0, 0, 0, 0);
        if (gr < N)
          an[i] = *(const uint4*)(AGG + (size_t)gr * KAGG + (kt + 1) * 128 + kk * 32 + lg * 8);
      }
    }
    const unsigned char* lds = (const unsigned char*)bbuf[cur];
#pragma unroll
    for (int kk = 0; kk < 4; ++kk) {
      short8 a0 = *(const short8*)&ac[0 * 4 + kk];
      short8 a1 = *(const short8*)&ac[1 * 4 + kk];
#pragma unroll
      for (int n = 0; n < 8; ++n) {
        short8 b = *(const short8*)(lds + (kk * 8 + n) * 1024 + lane * 16);
        acc[0][n] = __builtin_amdgcn_mfma_f32_16x16x32_bf16(a0, b, acc[0][n], 0, 0, 0);
        acc[1][n] = __builtin_amdgcn_mfma_f32_16x16x32_bf16(a1, b, acc[1][n], 0, 0, 0);
      }
    }
    if (kt < 15) {
#pragma unroll
      for (int i = 0; i < 8; ++i) bbuf[cur ^ 1][i * 256 + tid] = bn[i];
      __syncthreads();
      cur ^= 1;
#pragma unroll
      for (int i = 0; i < 8; ++i) ac[i] = an[i];
    }
  }

  float cb[8], gm[8], bt[8];
#pragma unroll
  for (int n = 0; n < 8; ++n) {
    cb[n] = cbias[n * 16 + lr];
    gm[n] = gamma[n * 16 + lr];
    bt[n] = beta[n * 16 + lr];
  }
#pragma unroll
  for (int m = 0; m < 2; ++m)
#pragma unroll
    for (int rr = 0; rr < 4; ++rr) {
      float y[8];
      float s = 0.f, ss = 0.f;
#pragma unroll
      for (int n = 0; n < 8; ++n) {
        y[n] = acc[m][n][rr] + cb[n];
        s += y[n];
        ss += y[n] * y[n];
      }
#pragma unroll
      for (int mask = 1; mask <= 8; mask <<= 1) {
        s += __shfl_xor(s, mask);
        ss += __shfl_xor(ss, mask);
      }
      float mean = s * (1.f / 128.f);
      float var = ss * (1.f / 128.f) - mean * mean;
      float rstd = rsqrtf(var + 1e-5f);
      int gr = wrow + m * 16 + lg * 4 + rr;
      if (gr < N) {
#pragma unroll
        for (int n = 0; n < 8; ++n) {
          float v = (y[n] - mean) * rstd * gm[n] + bt[n];
          out[(size_t)gr * DD + n * 16 + lr] = fmaxf(0.f, v);
        }
      }
    }
}

extern "C" void kernel_launch(void* const* d_in, const int* in_sizes, int n_in,
                              void* d_out, int out_size, void* d_ws, size_t ws_size,
                              hipStream_t stream) {
  const float* x      = (const float*)d_in[0];
  const int*   ei     = (const int*)d_in[1];
  const int*   attr   = (const int*)d_in[2];
  const float* Wg     = (const float*)d_in[3];
  const float* a_src  = (const float*)d_in[4];
  const float* a_dst  = (const float*)d_in[5];
  const float* b_gat  = (const float*)d_in[6];
  const float* etw    = (const float*)d_in[7];
  const float* W_fuse = (const float*)d_in[8];
  const float* b_fuse = (const float*)d_in[9];
  const float* gamma  = (const float*)d_in[10];
  const float* beta   = (const float*)d_in[11];

  const int N = in_sizes[0] / DD;
  const int E = in_sizes[2];
  const int* src = ei;
  const int* dst = ei + E;
  const int M = TT * N;

  char* ws = (char*)d_ws;
  size_t off = 0;
  auto alloc = [&](size_t bytes) {
    void* p = ws + off;
    off += (bytes + 255) & ~(size_t)255;
    return p;
  };
  unsigned short* AGG   = (unsigned short*)alloc((size_t)N * KAGG * 2);      // 204.8MB
  unsigned short* xb    = (unsigned short*)alloc((size_t)N * DD * 2);        // 12.8MB
  unsigned short* Gfrag = (unsigned short*)alloc((size_t)512 * 512 * 2);     // 512KB
  unsigned short* Pall  = (unsigned short*)alloc((size_t)32 * DD * 2);       // 8KB
  float* cbias          = (float*)alloc(128 * sizeof(float));
  float* as_            = (float*)alloc((size_t)TT * N * 4 * sizeof(float)); // 3.2MB
  float* ad_            = (float*)alloc((size_t)TT * N * 4 * sizeof(float));
  int* deg              = (int*)alloc((size_t)(M + 1) * sizeof(int));        // +1 = gcur
  int* rowptr           = (int*)alloc((size_t)M * sizeof(int));
  int* cursor           = (int*)alloc((size_t)M * sizeof(int));
  int* slist            = (int*)alloc((size_t)E * sizeof(int));              // 1.3MB

  hipMemsetAsync(deg, 0, (size_t)(M + 1) * sizeof(int), stream);

  int total4x = N * DD / 4;
  int nconv = (total4x + 255) / 256;
  int nhist = (E + 255) / 256;
  prologue_kernel<<<nconv + 1041 + nhist, 256, 0, stream>>>(
      x, xb, total4x, Wg, a_src, a_dst, W_fuse, b_gat, etw, b_fuse,
      Gfrag, Pall, cbias, dst, attr, deg, E, N);

  scanfused_kernel<<<(M + 1023) / 1024, 1024, 0, stream>>>(deg, rowptr, cursor,
                                                           deg + M, M);

  int nalpha = (N + 127) / 128;
  scatter_alpha_kernel<<<nhist + nalpha, 256, 0, stream>>>(
      src, dst, attr, cursor, slist, xb, Pall, as_, ad_, E, N);

  dim3 ggrid((N + 15) / 16, TT);
  gather_kernel<<<ggrid, 256, 0, stream>>>(slist, rowptr, deg, as_, ad_, xb, AGG, N);

  gemmln_kernel<<<(N + 127) / 128, 256, 0, stream>>>(AGG, Gfrag, cbias, gamma, beta,
                                                     (float*)d_out, N);
}